// Round 2
// baseline (708.755 us; speedup 1.0000x reference)
//
#include <hip/hip_runtime.h>
#include <hip/hip_bf16.h>
#include <stdint.h>

// ---------------------------------------------------------------------------
// TemporalAttention: context = softmax((query@Wq+bq)(keys@Wk+bk)^T/sqrt(512)) @ ((keys@Wk+bk)@Wv+bv)
// B=16, LQ=1024, LK=4096, D=512.  All-bf16 MFMA pipeline with fp32 accum.
// ---------------------------------------------------------------------------

typedef __attribute__((ext_vector_type(8))) short bf16x8;
typedef __attribute__((ext_vector_type(4))) float f32x4;
typedef __attribute__((ext_vector_type(8))) unsigned short ushort8v;
typedef __attribute__((ext_vector_type(4))) unsigned short ushort4v;

__device__ __forceinline__ unsigned short f2bf(float f) {
  union { float f; unsigned int u; } x{f};
  unsigned int r = x.u + 0x7FFFu + ((x.u >> 16) & 1u);
  return (unsigned short)(r >> 16);
}
__device__ __forceinline__ float bf2f(unsigned short h) {
  union { unsigned int u; float f; } x{(unsigned int)h << 16};
  return x.f;
}

#define GLOAD_LDS16(gptr, lptr)                                                  \
  __builtin_amdgcn_global_load_lds((const __attribute__((address_space(1))) void*)(gptr), \
                                   (__attribute__((address_space(3))) void*)(lptr), 16, 0, 0)

// ---------------------------------------------------------------------------
// Cast fp32 -> bf16 (vectorized, grid-stride)
// ---------------------------------------------------------------------------
__global__ __launch_bounds__(256) void cast_bf16_kernel(const float* __restrict__ in,
                                                        unsigned short* __restrict__ out,
                                                        long n) {
  long i = ((long)blockIdx.x * blockDim.x + threadIdx.x) * 8;
  long stride = (long)gridDim.x * blockDim.x * 8;
  for (; i < n; i += stride) {
    const float4* p = (const float4*)(in + i);
    float4 a = p[0], b = p[1];
    ushort8v o;
    o[0] = f2bf(a.x); o[1] = f2bf(a.y); o[2] = f2bf(a.z); o[3] = f2bf(a.w);
    o[4] = f2bf(b.x); o[5] = f2bf(b.y); o[6] = f2bf(b.z); o[7] = f2bf(b.w);
    *(ushort8v*)(out + i) = o;
  }
}

// ---------------------------------------------------------------------------
// Transpose 512x512 fp32 W -> bf16 W^T (3 matrices via blockIdx.z)
// ---------------------------------------------------------------------------
__global__ __launch_bounds__(256) void transpose_w_kernel(const float* __restrict__ W0,
                                                          const float* __restrict__ W1,
                                                          const float* __restrict__ W2,
                                                          unsigned short* __restrict__ T0,
                                                          unsigned short* __restrict__ T1,
                                                          unsigned short* __restrict__ T2) {
  const float* W = (blockIdx.z == 0) ? W0 : (blockIdx.z == 1) ? W1 : W2;
  unsigned short* T = (blockIdx.z == 0) ? T0 : (blockIdx.z == 1) ? T1 : T2;
  __shared__ float tile[32][33];
  int tx = threadIdx.x & 31, ty = threadIdx.x >> 5;  // 32 x 8
  int gx = blockIdx.x * 32 + tx;
  int gy0 = blockIdx.y * 32;
#pragma unroll
  for (int i = 0; i < 32; i += 8) tile[ty + i][tx] = W[(size_t)(gy0 + ty + i) * 512 + gx];
  __syncthreads();
  int ox = blockIdx.y * 32 + tx;
  int oy0 = blockIdx.x * 32;
#pragma unroll
  for (int i = 0; i < 32; i += 8)
    T[(size_t)(oy0 + ty + i) * 512 + ox] = f2bf(tile[tx][ty + i]);
}

// ---------------------------------------------------------------------------
// NT GEMM: C[m][n] = sum_k A[m][k] * Bt[n][k]   (A, Bt bf16 row-major, fp32 acc)
// OUT_MODE: 0 = bf16 C[m][n]; 1 = bf16 transposed vT special (b=m>>12, writes
//           C[(b*512+n)*4096 + (m&4095)]); 2 = f32 C[m][n]
// epilogue: out = acc*scale + bias[n]
// Tile 128x128, BK=64, 256 threads (4 waves, 2x2), 16x16x32 bf16 MFMA.
// ---------------------------------------------------------------------------
template <int OUT_MODE, bool HAS_BIAS>
__global__ __launch_bounds__(256, 2) void gemm_nt(const unsigned short* __restrict__ A,
                                                  const unsigned short* __restrict__ Bt,
                                                  const float* __restrict__ bias,
                                                  void* __restrict__ Cout,
                                                  int M, int N, int K, float scale,
                                                  long sA, long sB, long sC) {
  __shared__ __align__(16) unsigned short lA[2][128][64];
  __shared__ __align__(16) unsigned short lB[2][128][64];
  const int tid = threadIdx.x;
  const int lane = tid & 63;
  const int wave = tid >> 6;
  const int z = blockIdx.z;
  const unsigned short* Ab = A + (size_t)z * sA;
  const unsigned short* Bb = Bt + (size_t)z * sB;
  const int m0 = blockIdx.y * 128;
  const int n0 = blockIdx.x * 128;

  f32x4 acc[4][4] = {};

  auto stage = [&](int buf, int kt) {
    const int k0 = kt * 64;
#pragma unroll
    for (int p = 0; p < 4; ++p) {
      int c = p * 4 + wave;          // chunk 0..15, 1KB each
      int f = c * 512 + lane * 8;    // flat ushort index
      int row = f >> 6, col = f & 63;
      const unsigned short* gA = Ab + (size_t)(m0 + row) * K + (k0 + col);
      const unsigned short* gB = Bb + (size_t)(n0 + row) * K + (k0 + col);
      GLOAD_LDS16(gA, &lA[buf][0][0] + c * 512);
      GLOAD_LDS16(gB, &lB[buf][0][0] + c * 512);
    }
  };

  const int wm = wave >> 1, wn = wave & 1;
  const int lr = lane & 15;
  const int lk = (lane >> 4) << 3;

  const int KT = K >> 6;
  stage(0, 0);
  __syncthreads();
  int cur = 0;
  for (int kt = 0; kt < KT; ++kt) {
    if (kt + 1 < KT) stage(cur ^ 1, kt + 1);
#pragma unroll
    for (int kk = 0; kk < 64; kk += 32) {
      bf16x8 af[4], bfv[4];
#pragma unroll
      for (int i = 0; i < 4; ++i)
        af[i] = *(const bf16x8*)&lA[cur][wm * 64 + i * 16 + lr][kk + lk];
#pragma unroll
      for (int j = 0; j < 4; ++j)
        bfv[j] = *(const bf16x8*)&lB[cur][wn * 64 + j * 16 + lr][kk + lk];
#pragma unroll
      for (int i = 0; i < 4; ++i)
#pragma unroll
        for (int j = 0; j < 4; ++j)
          acc[i][j] = __builtin_amdgcn_mfma_f32_16x16x32_bf16(af[i], bfv[j], acc[i][j], 0, 0, 0);
    }
    __syncthreads();
    cur ^= 1;
  }

  // epilogue
  const int ci = lane & 15;
  const int ri = (lane >> 4) * 4;
#pragma unroll
  for (int i = 0; i < 4; ++i) {
#pragma unroll
    for (int j = 0; j < 4; ++j) {
      int gm = m0 + wm * 64 + i * 16 + ri;
      int gn = n0 + wn * 64 + j * 16 + ci;
      float bv_ = HAS_BIAS ? bias[gn] : 0.f;
      f32x4 a = acc[i][j];
      if (OUT_MODE == 0) {
        unsigned short* C = (unsigned short*)Cout + (size_t)z * sC;
#pragma unroll
        for (int r = 0; r < 4; ++r)
          C[(size_t)(gm + r) * N + gn] = f2bf(a[r] * scale + bv_);
      } else if (OUT_MODE == 2) {
        float* C = (float*)Cout + (size_t)z * sC;
#pragma unroll
        for (int r = 0; r < 4; ++r)
          C[(size_t)(gm + r) * N + gn] = a[r] * scale + bv_;
      } else {  // vT: input rows m are kv rows over all batches, cols n are dims
        unsigned short* C = (unsigned short*)Cout;
        int b_ = gm >> 12;
        int ml = gm & 4095;
        ushort4v pk;
#pragma unroll
        for (int r = 0; r < 4; ++r) pk[r] = f2bf(a[r] * scale + bv_);
        *(ushort4v*)&C[((size_t)b_ * 512 + gn) * 4096 + ml] = pk;
      }
    }
  }
}

// ---------------------------------------------------------------------------
// Row softmax in-place on bf16 scores, one block (256 thr) per row of 4096
// ---------------------------------------------------------------------------
__global__ __launch_bounds__(256) void softmax_kernel(unsigned short* __restrict__ s) {
  size_t row = blockIdx.x;
  unsigned short* p = s + row * 4096;
  int tid = threadIdx.x;
  int lane = tid & 63, wave = tid >> 6;

  ushort8v d0 = ((ushort8v*)p)[tid * 2];
  ushort8v d1 = ((ushort8v*)p)[tid * 2 + 1];
  float v[16];
#pragma unroll
  for (int j = 0; j < 8; ++j) { v[j] = bf2f(d0[j]); v[8 + j] = bf2f(d1[j]); }

  float m = v[0];
#pragma unroll
  for (int j = 1; j < 16; ++j) m = fmaxf(m, v[j]);
  for (int off = 32; off > 0; off >>= 1) m = fmaxf(m, __shfl_xor(m, off));
  __shared__ float redm[4], reds[4];
  if (lane == 0) redm[wave] = m;
  __syncthreads();
  m = fmaxf(fmaxf(redm[0], redm[1]), fmaxf(redm[2], redm[3]));

  float sum = 0.f;
#pragma unroll
  for (int j = 0; j < 16; ++j) { v[j] = __expf(v[j] - m); sum += v[j]; }
  for (int off = 32; off > 0; off >>= 1) sum += __shfl_xor(sum, off);
  if (lane == 0) reds[wave] = sum;
  __syncthreads();
  sum = reds[0] + reds[1] + reds[2] + reds[3];
  float r = 1.0f / sum;

#pragma unroll
  for (int j = 0; j < 8; ++j) { d0[j] = f2bf(v[j] * r); d1[j] = f2bf(v[8 + j] * r); }
  ((ushort8v*)p)[tid * 2] = d0;
  ((ushort8v*)p)[tid * 2 + 1] = d1;
}

// ---------------------------------------------------------------------------
extern "C" void kernel_launch(void* const* d_in, const int* in_sizes, int n_in,
                              void* d_out, int out_size, void* d_ws, size_t ws_size,
                              hipStream_t stream) {
  const float* query = (const float*)d_in[0];  // [16,1024,512]
  const float* keys  = (const float*)d_in[1];  // [16,4096,512]
  const float* Wq = (const float*)d_in[2];
  const float* bq = (const float*)d_in[3];
  const float* Wk = (const float*)d_in[4];
  const float* bk = (const float*)d_in[5];
  const float* Wv = (const float*)d_in[6];
  const float* bv = (const float*)d_in[7];
  float* out = (float*)d_out;

  char* w = (char*)d_ws;
  // scores region (134,217,728 B) overlaps the dead cast buffers:
  unsigned short* scores   = (unsigned short*)w;
  unsigned short* query_bf = (unsigned short*)w;                    // 16 MB (dead after q-proj)
  unsigned short* keys_bf  = (unsigned short*)(w + 16777216);       // 64 MB (dead after k-proj)
  unsigned short* q_bf = (unsigned short*)(w + 134217728);          // 16 MB
  unsigned short* k_bf = (unsigned short*)(w + 134217728 + 16777216);            // 64 MB
  unsigned short* vT   = (unsigned short*)(w + 134217728 + 16777216 + 67108864); // 64 MB
  unsigned short* WqT  = (unsigned short*)(w + 285212672);
  unsigned short* WkT  = WqT + 262144;
  unsigned short* WvT  = WkT + 262144;

  const float scale = 0.04419417382415922f;  // 1/sqrt(512)

  cast_bf16_kernel<<<1024, 256, 0, stream>>>(query, query_bf, 8388608L);
  cast_bf16_kernel<<<2048, 256, 0, stream>>>(keys, keys_bf, 33554432L);
  transpose_w_kernel<<<dim3(16, 16, 3), 256, 0, stream>>>(Wq, Wk, Wv, WqT, WkT, WvT);

  // q = query@Wq + bq   [16384 x 512]
  gemm_nt<0, true><<<dim3(4, 128, 1), 256, 0, stream>>>(query_bf, WqT, bq, q_bf,
                                                        16384, 512, 512, 1.f, 0, 0, 0);
  // k = keys@Wk + bk    [65536 x 512]
  gemm_nt<0, true><<<dim3(4, 512, 1), 256, 0, stream>>>(keys_bf, WkT, bk, k_bf,
                                                        65536, 512, 512, 1.f, 0, 0, 0);
  // v = k@Wv + bv, stored transposed per batch: vT[b][dim][kvpos]
  gemm_nt<1, true><<<dim3(4, 512, 1), 256, 0, stream>>>(k_bf, WvT, bv, vT,
                                                        65536, 512, 512, 1.f, 0, 0, 0);
  // scores = q @ k^T * scale   per batch [1024 x 4096]
  gemm_nt<0, false><<<dim3(32, 8, 16), 256, 0, stream>>>(q_bf, k_bf, nullptr, scores,
                                                         1024, 4096, 512, scale,
                                                         524288, 2097152, 4194304);
  // softmax rows
  softmax_kernel<<<16384, 256, 0, stream>>>(scores);
  // context = attn @ v  per batch [1024 x 512] (NT against vT), fp32 out
  gemm_nt<2, false><<<dim3(4, 8, 16), 256, 0, stream>>>(scores, vT, nullptr, out,
                                                        1024, 512, 4096, 1.f,
                                                        4194304, 2097152, 524288);
  (void)in_sizes; (void)n_in; (void)out_size; (void)ws_size;
}

// Round 3
// 702.878 us; speedup vs baseline: 1.0084x; 1.0084x over previous
//
#include <hip/hip_runtime.h>
#include <hip/hip_bf16.h>
#include <stdint.h>

// ---------------------------------------------------------------------------
// TemporalAttention fused pipeline:
//   q = (query@Wq+bq)*scale ; k = keys@Wk+bk ; v = k@Wv+bv (vT materialized)
//   context = softmax(q k^T) v   via flash-attention fused kernel.
// B=16, LQ=1024, LK=4096, D=512. bf16 MFMA, fp32 accum.
// ---------------------------------------------------------------------------

typedef __attribute__((ext_vector_type(8))) short bf16x8;
typedef __attribute__((ext_vector_type(4))) float f32x4;
typedef __attribute__((ext_vector_type(8))) unsigned short ushort8v;
typedef __attribute__((ext_vector_type(4))) unsigned short ushort4v;

__device__ __forceinline__ unsigned short f2bf(float f) {
  union { float f; unsigned int u; } x{f};
  unsigned int r = x.u + 0x7FFFu + ((x.u >> 16) & 1u);
  return (unsigned short)(r >> 16);
}
__device__ __forceinline__ float bf2f(unsigned short h) {
  union { unsigned int u; float f; } x{(unsigned int)h << 16};
  return x.f;
}

#define GLOAD_LDS16(gptr, lptr)                                                  \
  __builtin_amdgcn_global_load_lds((const __attribute__((address_space(1))) void*)(gptr), \
                                   (__attribute__((address_space(3))) void*)(lptr), 16, 0, 0)

// ---------------------------------------------------------------------------
// Cast fp32 -> bf16 (vectorized, grid-stride)
// ---------------------------------------------------------------------------
__global__ __launch_bounds__(256) void cast_bf16_kernel(const float* __restrict__ in,
                                                        unsigned short* __restrict__ out,
                                                        long n) {
  long i = ((long)blockIdx.x * blockDim.x + threadIdx.x) * 8;
  long stride = (long)gridDim.x * blockDim.x * 8;
  for (; i < n; i += stride) {
    const float4* p = (const float4*)(in + i);
    float4 a = p[0], b = p[1];
    ushort8v o;
    o[0] = f2bf(a.x); o[1] = f2bf(a.y); o[2] = f2bf(a.z); o[3] = f2bf(a.w);
    o[4] = f2bf(b.x); o[5] = f2bf(b.y); o[6] = f2bf(b.z); o[7] = f2bf(b.w);
    *(ushort8v*)(out + i) = o;
  }
}

// ---------------------------------------------------------------------------
// Transpose 512x512 fp32 W -> bf16 W^T (3 matrices via blockIdx.z)
// ---------------------------------------------------------------------------
__global__ __launch_bounds__(256) void transpose_w_kernel(const float* __restrict__ W0,
                                                          const float* __restrict__ W1,
                                                          const float* __restrict__ W2,
                                                          unsigned short* __restrict__ T0,
                                                          unsigned short* __restrict__ T1,
                                                          unsigned short* __restrict__ T2) {
  const float* W = (blockIdx.z == 0) ? W0 : (blockIdx.z == 1) ? W1 : W2;
  unsigned short* T = (blockIdx.z == 0) ? T0 : (blockIdx.z == 1) ? T1 : T2;
  __shared__ float tile[32][33];
  int tx = threadIdx.x & 31, ty = threadIdx.x >> 5;  // 32 x 8
  int gx = blockIdx.x * 32 + tx;
  int gy0 = blockIdx.y * 32;
#pragma unroll
  for (int i = 0; i < 32; i += 8) tile[ty + i][tx] = W[(size_t)(gy0 + ty + i) * 512 + gx];
  __syncthreads();
  int ox = blockIdx.y * 32 + tx;
  int oy0 = blockIdx.x * 32;
#pragma unroll
  for (int i = 0; i < 32; i += 8)
    T[(size_t)(oy0 + ty + i) * 512 + ox] = f2bf(tile[tx][ty + i]);
}

// ---------------------------------------------------------------------------
// NT GEMM (projections): C[m][n] = (sum_k A[m][k]*Bt[n][k] + bias[n]) * scale
// OUT_MODE: 0 = bf16 C[m][n]; 1 = bf16 vT special (b=m>>12, C[(b*512+n)*4096+(m&4095)])
// Tile 128x128, BK=64, 256 threads (4 waves, 2x2), 16x16x32 bf16 MFMA.
// ---------------------------------------------------------------------------
template <int OUT_MODE>
__global__ __launch_bounds__(256, 2) void gemm_nt(const unsigned short* __restrict__ A,
                                                  const unsigned short* __restrict__ Bt,
                                                  const float* __restrict__ bias,
                                                  void* __restrict__ Cout,
                                                  int M, int N, int K, float scale) {
  __shared__ __align__(16) unsigned short lA[2][128][64];
  __shared__ __align__(16) unsigned short lB[2][128][64];
  const int tid = threadIdx.x;
  const int lane = tid & 63;
  const int wave = tid >> 6;
  const int m0 = blockIdx.y * 128;
  const int n0 = blockIdx.x * 128;

  f32x4 acc[4][4] = {};

  auto stage = [&](int buf, int kt) {
    const int k0 = kt * 64;
#pragma unroll
    for (int p = 0; p < 4; ++p) {
      int c = p * 4 + wave;          // chunk 0..15, 1KB each
      int f = c * 512 + lane * 8;    // flat ushort index
      int row = f >> 6, col = f & 63;
      const unsigned short* gA = A + (size_t)(m0 + row) * K + (k0 + col);
      const unsigned short* gB = Bt + (size_t)(n0 + row) * K + (k0 + col);
      GLOAD_LDS16(gA, &lA[buf][0][0] + c * 512);
      GLOAD_LDS16(gB, &lB[buf][0][0] + c * 512);
    }
  };

  const int wm = wave >> 1, wn = wave & 1;
  const int lr = lane & 15;
  const int lk = (lane >> 4) << 3;

  const int KT = K >> 6;
  stage(0, 0);
  __syncthreads();
  int cur = 0;
  for (int kt = 0; kt < KT; ++kt) {
    if (kt + 1 < KT) stage(cur ^ 1, kt + 1);
#pragma unroll
    for (int kk = 0; kk < 64; kk += 32) {
      bf16x8 af[4], bfv[4];
#pragma unroll
      for (int i = 0; i < 4; ++i)
        af[i] = *(const bf16x8*)&lA[cur][wm * 64 + i * 16 + lr][kk + lk];
#pragma unroll
      for (int j = 0; j < 4; ++j)
        bfv[j] = *(const bf16x8*)&lB[cur][wn * 64 + j * 16 + lr][kk + lk];
#pragma unroll
      for (int i = 0; i < 4; ++i)
#pragma unroll
        for (int j = 0; j < 4; ++j)
          acc[i][j] = __builtin_amdgcn_mfma_f32_16x16x32_bf16(af[i], bfv[j], acc[i][j], 0, 0, 0);
    }
    __syncthreads();
    cur ^= 1;
  }

  const int ci = lane & 15;
  const int ri = (lane >> 4) * 4;
#pragma unroll
  for (int i = 0; i < 4; ++i) {
#pragma unroll
    for (int j = 0; j < 4; ++j) {
      int gm = m0 + wm * 64 + i * 16 + ri;
      int gn = n0 + wn * 64 + j * 16 + ci;
      float bv_ = bias[gn];
      f32x4 a = acc[i][j];
      if (OUT_MODE == 0) {
        unsigned short* C = (unsigned short*)Cout;
#pragma unroll
        for (int r = 0; r < 4; ++r)
          C[(size_t)(gm + r) * N + gn] = f2bf((a[r] + bv_) * scale);
      } else {  // vT: rows m are kv rows over all batches, cols n are dims
        unsigned short* C = (unsigned short*)Cout;
        int b_ = gm >> 12;
        int ml = gm & 4095;
        ushort4v pk;
#pragma unroll
        for (int r = 0; r < 4; ++r) pk[r] = f2bf((a[r] + bv_) * scale);
        *(ushort4v*)&C[((size_t)b_ * 512 + gn) * 4096 + ml] = pk;
      }
    }
  }
}

// ---------------------------------------------------------------------------
// Flash attention: out[b][q][d] = softmax_kv(qk^T) @ v
//   q: [16][1024][512] bf16 (scale pre-folded), k: [16][4096][512] bf16,
//   vT: [16][512][4096] bf16, out fp32.
// Block: 512 thr (8 waves), QBLK=64 q-rows, KVBLK=128, 32 KV tiles.
// Swapped QK^T (S^T = mfma(K,Q)) so softmax kv-axis is lane-local.
// lQ/lK/lP XOR-swizzled (byte ^= (row&7)<<4); gload_lds sources pre-swizzled.
// ---------------------------------------------------------------------------
__global__ __launch_bounds__(512, 1) void flash_attn(const unsigned short* __restrict__ q,
                                                     const unsigned short* __restrict__ k,
                                                     const unsigned short* __restrict__ vT,
                                                     float* __restrict__ out) {
  __shared__ __align__(16) unsigned short lQ[64 * 512];   // 64 KB
  __shared__ __align__(16) unsigned short lK[2][128 * 64]; // 32 KB
  __shared__ __align__(16) unsigned short lP[64 * 128];   // 16 KB
  __shared__ float redm[64 * 8], reds[64 * 8];            // 4 KB
  __shared__ float m_s[64], rs_s[64];                     // 512 B

  const int tid = threadIdx.x;
  const int lane = tid & 63;
  const int w = tid >> 6;
  const int bid = blockIdx.x;
  // bijective XCD swizzle: XCD c (= bid%8) serves batches {2c, 2c+1}
  const int b = (bid & 7) * 2 + ((bid >> 3) >> 4);
  const int qt = (bid >> 3) & 15;

  const unsigned short* Qb = q + ((size_t)b * 1024 + qt * 64) * 512;
  const unsigned short* Kb = k + (size_t)b * 4096 * 512;
  const unsigned short* Vb = vT + (size_t)b * 512 * 4096;

  auto stageK = [&](int buf, int t2, int c2) {
    const int kv0 = t2 * 128, kk = c2 * 64;
#pragma unroll
    for (int i = 0; i < 2; ++i) {
      int byte = (i * 512 + tid) * 16;
      int row = byte >> 7;
      int colB = byte & 127;
      int srcB = colB ^ ((row & 7) << 4);
      GLOAD_LDS16(Kb + (size_t)(kv0 + row) * 512 + kk + (srcB >> 1),
                  (char*)&lK[buf][0] + byte);
    }
  };

  // prologue: stage Q (swizzled source), K tile0 chunk0
#pragma unroll
  for (int i = 0; i < 8; ++i) {
    int byte = (i * 512 + tid) * 16;
    int row = byte >> 10;
    int colB = byte & 1023;
    int srcB = (colB & ~127) | ((colB & 127) ^ ((row & 7) << 4));
    GLOAD_LDS16(Qb + (size_t)row * 512 + (srcB >> 1), (char*)lQ + byte);
  }
  stageK(0, 0, 0);
  float m_run = -1e30f, l_run = 0.f;  // valid in wave 0 (lane j owns q-row j)
  float rs_reg = 0.f;
  __syncthreads();

  f32x4 acc_o[4][4] = {};  // [mf][nf]: q-row mf*16+(lane>>4)*4+r, d-col w*64+nf*16+(lane&15)
  int cur = 0;

  for (int t = 0; t < 32; ++t) {
    // ---- Phase A: S^T = K (tile t) @ Q^T ----
    f32x4 accS[4] = {};  // [nf]: kv-row w*16+(lane>>4)*4+r, q-col nf*16+(lane&15)
    for (int c = 0; c < 8; ++c) {
      if (c < 7) stageK(cur ^ 1, t, c + 1);
      else if (t < 31) stageK(cur ^ 1, t + 1, 0);
      const int rowK = w * 16 + (lane & 15);
#pragma unroll
      for (int ks = 0; ks < 2; ++ks) {
        int colKB = ((ks * 64 + ((lane >> 4) << 4)) ^ ((rowK & 7) << 4));
        bf16x8 afK = *(const bf16x8*)((char*)&lK[cur][0] + rowK * 128 + colKB);
#pragma unroll
        for (int nf = 0; nf < 4; ++nf) {
          int rowQ = nf * 16 + (lane & 15);
          int colQB = c * 128 + ((ks * 64 + ((lane >> 4) << 4)) ^ ((rowQ & 7) << 4));
          bf16x8 bfQ = *(const bf16x8*)((char*)lQ + rowQ * 1024 + colQB);
          accS[nf] = __builtin_amdgcn_mfma_f32_16x16x32_bf16(afK, bfQ, accS[nf], 0, 0, 0);
        }
      }
      __syncthreads();
      cur ^= 1;
    }

    // ---- Phase B: online softmax ----
    // per-wave max over this wave's 16 kv rows (4 in-reg + lanes l^16, l^32)
#pragma unroll
    for (int nf = 0; nf < 4; ++nf) {
      f32x4 s = accS[nf];
      float mx = fmaxf(fmaxf(s[0], s[1]), fmaxf(s[2], s[3]));
      mx = fmaxf(mx, __shfl_xor(mx, 16));
      mx = fmaxf(mx, __shfl_xor(mx, 32));
      if (lane < 16) redm[(nf * 16 + lane) * 8 + w] = mx;
    }
    __syncthreads();
    if (w == 0) {  // lane j owns q-row j
      f32x4 a = *(const f32x4*)&redm[lane * 8];
      f32x4 a2 = *(const f32x4*)&redm[lane * 8 + 4];
      float tmax = fmaxf(fmaxf(fmaxf(a[0], a[1]), fmaxf(a[2], a[3])),
                         fmaxf(fmaxf(a2[0], a2[1]), fmaxf(a2[2], a2[3])));
      float m_new = fmaxf(m_run, tmax);
      rs_reg = __expf(m_run - m_new);
      m_run = m_new;
      m_s[lane] = m_new;
      rs_s[lane] = rs_reg;
    }
    __syncthreads();
    // exp, row-sum, pack P -> LDS
#pragma unroll
    for (int nf = 0; nf < 4; ++nf) {
      int qrow = nf * 16 + (lane & 15);
      float mq = m_s[qrow];
      f32x4 s = accS[nf];
      ushort4v pk;
      float sum = 0.f;
#pragma unroll
      for (int r = 0; r < 4; ++r) {
        float p = __expf(s[r] - mq);
        sum += p;
        pk[r] = f2bf(p);
      }
      sum += __shfl_xor(sum, 16);
      sum += __shfl_xor(sum, 32);
      if (lane < 16) reds[qrow * 8 + w] = sum;
      int colB = (w * 32 + ((lane >> 4) << 3)) ^ ((qrow & 7) << 4);
      *(ushort4v*)((char*)lP + qrow * 256 + colB) = pk;
    }
    __syncthreads();
    if (w == 0) {
      f32x4 a = *(const f32x4*)&reds[lane * 8];
      f32x4 a2 = *(const f32x4*)&reds[lane * 8 + 4];
      float tsum = (a[0] + a[1] + a[2] + a[3]) + (a2[0] + a2[1] + a2[2] + a2[3]);
      l_run = l_run * rs_reg + tsum;
    }
    // rescale output accumulator
#pragma unroll
    for (int mf = 0; mf < 4; ++mf) {
      f32x4 rsv = *(const f32x4*)&rs_s[(mf << 4) + ((lane >> 4) << 2)];
#pragma unroll
      for (int nf = 0; nf < 4; ++nf)
#pragma unroll
        for (int r = 0; r < 4; ++r) acc_o[mf][nf][r] *= rsv[r];
    }
    // ---- Phase C: PV (A = P from LDS, B = vT fragments direct from global) ----
#pragma unroll
    for (int ks = 0; ks < 4; ++ks) {
      bf16x8 bv_[4];
#pragma unroll
      for (int nf = 0; nf < 4; ++nf) {
        int d = (w << 6) + (nf << 4) + (lane & 15);
        bv_[nf] = *(const bf16x8*)(Vb + (size_t)d * 4096 + t * 128 + (ks << 5) + ((lane >> 4) << 3));
      }
#pragma unroll
      for (int mf = 0; mf < 4; ++mf) {
        int qr = (mf << 4) + (lane & 15);
        int colB = ((ks << 6) + ((lane >> 4) << 4)) ^ ((qr & 7) << 4);
        bf16x8 ap = *(const bf16x8*)((char*)lP + qr * 256 + colB);
#pragma unroll
        for (int nf = 0; nf < 4; ++nf)
          acc_o[mf][nf] = __builtin_amdgcn_mfma_f32_16x16x32_bf16(ap, bv_[nf], acc_o[mf][nf], 0, 0, 0);
      }
    }
    // lP not rewritten until next tile's Phase B (>=2 barriers away): safe.
  }

  // ---- epilogue: divide by row-sum, store fp32 ----
  if (w == 0) rs_s[lane] = 1.f / l_run;
  __syncthreads();
#pragma unroll
  for (int mf = 0; mf < 4; ++mf) {
    f32x4 il = *(const f32x4*)&rs_s[(mf << 4) + ((lane >> 4) << 2)];
#pragma unroll
    for (int nf = 0; nf < 4; ++nf) {
      int d = (w << 6) + (nf << 4) + (lane & 15);
#pragma unroll
      for (int r = 0; r < 4; ++r) {
        int qr = (mf << 4) + ((lane >> 4) << 2) + r;
        out[((size_t)b * 1024 + qt * 64 + qr) * 512 + d] = acc_o[mf][nf][r] * il[r];
      }
    }
  }
}

// ---------------------------------------------------------------------------
extern "C" void kernel_launch(void* const* d_in, const int* in_sizes, int n_in,
                              void* d_out, int out_size, void* d_ws, size_t ws_size,
                              hipStream_t stream) {
  const float* query = (const float*)d_in[0];  // [16,1024,512]
  const float* keys  = (const float*)d_in[1];  // [16,4096,512]
  const float* Wq = (const float*)d_in[2];
  const float* bq = (const float*)d_in[3];
  const float* Wk = (const float*)d_in[4];
  const float* bk = (const float*)d_in[5];
  const float* Wv = (const float*)d_in[6];
  const float* bv = (const float*)d_in[7];
  float* out = (float*)d_out;

  char* w = (char*)d_ws;
  unsigned short* query_bf = (unsigned short*)w;                      // 16 MB
  unsigned short* keys_bf  = (unsigned short*)(w + 16777216);         // 64 MB
  unsigned short* q_bf = (unsigned short*)(w + 83886080);             // 16 MB
  unsigned short* k_bf = (unsigned short*)(w + 100663296);            // 64 MB
  unsigned short* vT   = (unsigned short*)(w + 167772160);            // 64 MB
  unsigned short* WqT  = (unsigned short*)(w + 234881024);
  unsigned short* WkT  = WqT + 262144;
  unsigned short* WvT  = WkT + 262144;

  const float scale = 0.04419417382415922f;  // 1/sqrt(512)

  cast_bf16_kernel<<<1024, 256, 0, stream>>>(query, query_bf, 8388608L);
  cast_bf16_kernel<<<2048, 256, 0, stream>>>(keys, keys_bf, 33554432L);
  transpose_w_kernel<<<dim3(16, 16, 3), 256, 0, stream>>>(Wq, Wk, Wv, WqT, WkT, WvT);

  // q = (query@Wq + bq) * scale   [16384 x 512]  (attention scale folded in)
  gemm_nt<0><<<dim3(4, 128), 256, 0, stream>>>(query_bf, WqT, bq, q_bf,
                                               16384, 512, 512, scale);
  // k = keys@Wk + bk    [65536 x 512]
  gemm_nt<0><<<dim3(4, 512), 256, 0, stream>>>(keys_bf, WkT, bk, k_bf,
                                               65536, 512, 512, 1.f);
  // v = k@Wv + bv, stored transposed per batch: vT[b][dim][kvpos]
  gemm_nt<1><<<dim3(4, 512), 256, 0, stream>>>(k_bf, WvT, bv, vT,
                                               65536, 512, 512, 1.f);
  // fused attention
  flash_attn<<<256, 512, 0, stream>>>(q_bf, k_bf, vT, out);

  (void)in_sizes; (void)n_in; (void)out_size; (void)ws_size;
}

// Round 4
// 665.894 us; speedup vs baseline: 1.0644x; 1.0555x over previous
//
#include <hip/hip_runtime.h>
#include <hip/hip_bf16.h>
#include <stdint.h>

// ---------------------------------------------------------------------------
// TemporalAttention fused pipeline:
//   q = (query@Wq+bq)*scale ; k = keys@Wk+bk ; v = k@Wv+bv (vT materialized)
//   context = softmax(q k^T) v   via flash-attention fused kernel.
// B=16, LQ=1024, LK=4096, D=512. bf16 MFMA, fp32 accum.
// ---------------------------------------------------------------------------

typedef __attribute__((ext_vector_type(8))) short bf16x8;
typedef __attribute__((ext_vector_type(4))) float f32x4;
typedef __attribute__((ext_vector_type(8))) unsigned short ushort8v;
typedef __attribute__((ext_vector_type(4))) unsigned short ushort4v;

__device__ __forceinline__ unsigned short f2bf(float f) {
  union { float f; unsigned int u; } x{f};
  unsigned int r = x.u + 0x7FFFu + ((x.u >> 16) & 1u);
  return (unsigned short)(r >> 16);
}
__device__ __forceinline__ float bf2f(unsigned short h) {
  union { unsigned int u; float f; } x{(unsigned int)h << 16};
  return x.f;
}

#define GLOAD_LDS16(gptr, lptr)                                                  \
  __builtin_amdgcn_global_load_lds((const __attribute__((address_space(1))) void*)(gptr), \
                                   (__attribute__((address_space(3))) void*)(lptr), 16, 0, 0)

// ---------------------------------------------------------------------------
// Cast fp32 -> bf16 (vectorized, grid-stride)
// ---------------------------------------------------------------------------
__global__ __launch_bounds__(256) void cast_bf16_kernel(const float* __restrict__ in,
                                                        unsigned short* __restrict__ out,
                                                        long n) {
  long i = ((long)blockIdx.x * blockDim.x + threadIdx.x) * 8;
  long stride = (long)gridDim.x * blockDim.x * 8;
  for (; i < n; i += stride) {
    const float4* p = (const float4*)(in + i);
    float4 a = p[0], b = p[1];
    ushort8v o;
    o[0] = f2bf(a.x); o[1] = f2bf(a.y); o[2] = f2bf(a.z); o[3] = f2bf(a.w);
    o[4] = f2bf(b.x); o[5] = f2bf(b.y); o[6] = f2bf(b.z); o[7] = f2bf(b.w);
    *(ushort8v*)(out + i) = o;
  }
}

// ---------------------------------------------------------------------------
// Transpose 512x512 fp32 W -> bf16 W^T (3 matrices via blockIdx.z)
// ---------------------------------------------------------------------------
__global__ __launch_bounds__(256) void transpose_w_kernel(const float* __restrict__ W0,
                                                          const float* __restrict__ W1,
                                                          const float* __restrict__ W2,
                                                          unsigned short* __restrict__ T0,
                                                          unsigned short* __restrict__ T1,
                                                          unsigned short* __restrict__ T2) {
  const float* W = (blockIdx.z == 0) ? W0 : (blockIdx.z == 1) ? W1 : W2;
  unsigned short* T = (blockIdx.z == 0) ? T0 : (blockIdx.z == 1) ? T1 : T2;
  __shared__ float tile[32][33];
  int tx = threadIdx.x & 31, ty = threadIdx.x >> 5;  // 32 x 8
  int gx = blockIdx.x * 32 + tx;
  int gy0 = blockIdx.y * 32;
#pragma unroll
  for (int i = 0; i < 32; i += 8) tile[ty + i][tx] = W[(size_t)(gy0 + ty + i) * 512 + gx];
  __syncthreads();
  int ox = blockIdx.y * 32 + tx;
  int oy0 = blockIdx.x * 32;
#pragma unroll
  for (int i = 0; i < 32; i += 8)
    T[(size_t)(oy0 + ty + i) * 512 + ox] = f2bf(tile[tx][ty + i]);
}

// ---------------------------------------------------------------------------
// NT GEMM (projections): C[m][n] = (sum_k A[m][k]*Bt[n][k] + bias[n]) * scale
// OUT_MODE: 0 = bf16 C[m][n]; 1 = bf16 vT special (b=m>>12, C[(b*512+n)*4096+(m&4095)])
// Tile 128x128, BK=64, 256 threads (4 waves, 2x2), 16x16x32 bf16 MFMA.
// ---------------------------------------------------------------------------
template <int OUT_MODE>
__global__ __launch_bounds__(256, 2) void gemm_nt(const unsigned short* __restrict__ A,
                                                  const unsigned short* __restrict__ Bt,
                                                  const float* __restrict__ bias,
                                                  void* __restrict__ Cout,
                                                  int M, int N, int K, float scale) {
  __shared__ __align__(16) unsigned short lA[2][128][64];
  __shared__ __align__(16) unsigned short lB[2][128][64];
  const int tid = threadIdx.x;
  const int lane = tid & 63;
  const int wave = tid >> 6;
  const int m0 = blockIdx.y * 128;
  const int n0 = blockIdx.x * 128;

  f32x4 acc[4][4] = {};

  auto stage = [&](int buf, int kt) {
    const int k0 = kt * 64;
#pragma unroll
    for (int p = 0; p < 4; ++p) {
      int c = p * 4 + wave;          // chunk 0..15, 1KB each
      int f = c * 512 + lane * 8;    // flat ushort index
      int row = f >> 6, col = f & 63;
      const unsigned short* gA = A + (size_t)(m0 + row) * K + (k0 + col);
      const unsigned short* gB = Bt + (size_t)(n0 + row) * K + (k0 + col);
      GLOAD_LDS16(gA, &lA[buf][0][0] + c * 512);
      GLOAD_LDS16(gB, &lB[buf][0][0] + c * 512);
    }
  };

  const int wm = wave >> 1, wn = wave & 1;
  const int lr = lane & 15;
  const int lk = (lane >> 4) << 3;

  const int KT = K >> 6;
  stage(0, 0);
  __syncthreads();
  int cur = 0;
  for (int kt = 0; kt < KT; ++kt) {
    if (kt + 1 < KT) stage(cur ^ 1, kt + 1);
#pragma unroll
    for (int kk = 0; kk < 64; kk += 32) {
      bf16x8 af[4], bfv[4];
#pragma unroll
      for (int i = 0; i < 4; ++i)
        af[i] = *(const bf16x8*)&lA[cur][wm * 64 + i * 16 + lr][kk + lk];
#pragma unroll
      for (int j = 0; j < 4; ++j)
        bfv[j] = *(const bf16x8*)&lB[cur][wn * 64 + j * 16 + lr][kk + lk];
#pragma unroll
      for (int i = 0; i < 4; ++i)
#pragma unroll
        for (int j = 0; j < 4; ++j)
          acc[i][j] = __builtin_amdgcn_mfma_f32_16x16x32_bf16(af[i], bfv[j], acc[i][j], 0, 0, 0);
    }
    __syncthreads();
    cur ^= 1;
  }

  const int ci = lane & 15;
  const int ri = (lane >> 4) * 4;
#pragma unroll
  for (int i = 0; i < 4; ++i) {
#pragma unroll
    for (int j = 0; j < 4; ++j) {
      int gm = m0 + wm * 64 + i * 16 + ri;
      int gn = n0 + wn * 64 + j * 16 + ci;
      float bv_ = bias[gn];
      f32x4 a = acc[i][j];
      if (OUT_MODE == 0) {
        unsigned short* C = (unsigned short*)Cout;
#pragma unroll
        for (int r = 0; r < 4; ++r)
          C[(size_t)(gm + r) * N + gn] = f2bf((a[r] + bv_) * scale);
      } else {  // vT: rows m are kv rows over all batches, cols n are dims
        unsigned short* C = (unsigned short*)Cout;
        int b_ = gm >> 12;
        int ml = gm & 4095;
        ushort4v pk;
#pragma unroll
        for (int r = 0; r < 4; ++r) pk[r] = f2bf((a[r] + bv_) * scale);
        *(ushort4v*)&C[((size_t)b_ * 512 + gn) * 4096 + ml] = pk;
      }
    }
  }
}

// ---------------------------------------------------------------------------
// Flash attention v2: out[b][q][d] = softmax_kv(qk^T) @ v
//   q: [16][1024][512] bf16 (scale pre-folded), k: [16][4096][512] bf16,
//   vT: [16][512][4096] bf16, out fp32.
// Block: 512 thr (8 waves), QBLK=64, KVBLK=128, 32 KV tiles.
// K and V fragments loaded DIRECT from global into VGPRs (L3-resident;
// no inter-wave sharing -> no staging barriers). Q in swizzled LDS.
// lP double-buffered; only 3 barriers per tile (softmax reductions).
// ---------------------------------------------------------------------------
__global__ __launch_bounds__(512, 1) void flash_attn(const unsigned short* __restrict__ q,
                                                     const unsigned short* __restrict__ k,
                                                     const unsigned short* __restrict__ vT,
                                                     float* __restrict__ out) {
  __shared__ __align__(16) unsigned short lQ[64 * 512];      // 64 KB, swizzled
  __shared__ __align__(16) unsigned short lP[2][64 * 128];   // 2 x 16 KB, swizzled
  __shared__ float redm[64 * 8], reds[64 * 8];               // 4 KB
  __shared__ float m_s[64], rs_s[64];                        // 512 B

  const int tid = threadIdx.x;
  const int lane = tid & 63;
  const int w = tid >> 6;
  const int g = lane >> 4;         // quarter-wave group 0..3
  const int r16 = lane & 15;
  const int bid = blockIdx.x;
  // bijective XCD swizzle: XCD c (= bid%8) serves batches {2c, 2c+1}
  const int b = (bid & 7) * 2 + ((bid >> 3) >> 4);
  const int qt = (bid >> 3) & 15;

  const unsigned short* Qb = q + ((size_t)b * 1024 + qt * 64) * 512;
  const unsigned short* Kb = k + (size_t)b * 4096 * 512;
  const unsigned short* Vb = vT + (size_t)b * 512 * 4096;

  // prologue: stage Q via gload_lds (pre-swizzled source, linear dest)
#pragma unroll
  for (int i = 0; i < 8; ++i) {
    int byte = (i * 512 + tid) * 16;
    int row = byte >> 10;
    int colB = byte & 1023;
    int srcB = (colB & ~127) | ((colB & 127) ^ ((row & 7) << 4));
    GLOAD_LDS16(Qb + (size_t)row * 512 + (srcB >> 1), (char*)lQ + byte);
  }
  float m_run = -1e30f, l_run = 0.f;  // valid in wave 0 (lane j owns q-row j)
  float rs_reg = 0.f;
  __syncthreads();

  f32x4 acc_o[4][4] = {};  // [mf][nf]: q-row mf*16+(lane>>4)*4+r, d-col w*64+nf*16+(lane&15)
  const int rowK = w * 16 + r16;   // this wave's kv-row (within tile)
  const unsigned short* KrowBase = Kb + (size_t)rowK * 512 + (g << 3);

  for (int t = 0; t < 32; ++t) {
    const int pbuf = t & 1;
    // ---- K fragments direct from global (16 independent b128 loads) ----
    const unsigned short* Krow = KrowBase + (size_t)t * 128 * 512;
    bf16x8 kf[16];
#pragma unroll
    for (int s = 0; s < 16; ++s) kf[s] = *(const bf16x8*)(Krow + s * 32);

    // ---- Phase A: S^T = K (tile t) @ Q^T  (no barriers) ----
    f32x4 accS[4] = {};  // [nf]: kv-row rowK, q-col nf*16+(lane&15)
#pragma unroll
    for (int s = 0; s < 16; ++s) {
#pragma unroll
      for (int nf = 0; nf < 4; ++nf) {
        int rowQ = nf * 16 + r16;
        int base = s * 64 + (g << 4);
        int colQB = (base & ~127) | ((base & 127) ^ ((rowQ & 7) << 4));
        bf16x8 qf = *(const bf16x8*)((char*)lQ + rowQ * 1024 + colQB);
        accS[nf] = __builtin_amdgcn_mfma_f32_16x16x32_bf16(kf[s], qf, accS[nf], 0, 0, 0);
      }
    }

    // ---- V fragments for this tile: issue early, consume in Phase C ----
    bf16x8 vf[4][4];  // [nf][ks]
#pragma unroll
    for (int nf = 0; nf < 4; ++nf) {
      int d = (w << 6) + (nf << 4) + r16;
      const unsigned short* Vrow = Vb + (size_t)d * 4096 + t * 128 + (g << 3);
#pragma unroll
      for (int ks = 0; ks < 4; ++ks) vf[nf][ks] = *(const bf16x8*)(Vrow + (ks << 5));
    }

    // ---- Phase B: online softmax ----
#pragma unroll
    for (int nf = 0; nf < 4; ++nf) {
      f32x4 s = accS[nf];
      float mx = fmaxf(fmaxf(s[0], s[1]), fmaxf(s[2], s[3]));
      mx = fmaxf(mx, __shfl_xor(mx, 16));
      mx = fmaxf(mx, __shfl_xor(mx, 32));
      if (lane < 16) redm[(nf * 16 + lane) * 8 + w] = mx;
    }
    __syncthreads();  // B1
    if (w == 0) {  // lane j owns q-row j
      f32x4 a = *(const f32x4*)&redm[lane * 8];
      f32x4 a2 = *(const f32x4*)&redm[lane * 8 + 4];
      float tmax = fmaxf(fmaxf(fmaxf(a[0], a[1]), fmaxf(a[2], a[3])),
                         fmaxf(fmaxf(a2[0], a2[1]), fmaxf(a2[2], a2[3])));
      float m_new = fmaxf(m_run, tmax);
      rs_reg = __expf(m_run - m_new);
      m_run = m_new;
      m_s[lane] = m_new;
      rs_s[lane] = rs_reg;
    }
    __syncthreads();  // B2
    // exp, row-sum, pack P -> lP[pbuf]
#pragma unroll
    for (int nf = 0; nf < 4; ++nf) {
      int qrow = nf * 16 + r16;
      float mq = m_s[qrow];
      f32x4 s = accS[nf];
      ushort4v pk;
      float sum = 0.f;
#pragma unroll
      for (int rr = 0; rr < 4; ++rr) {
        float p = __expf(s[rr] - mq);
        sum += p;
        pk[rr] = f2bf(p);
      }
      sum += __shfl_xor(sum, 16);
      sum += __shfl_xor(sum, 32);
      if (lane < 16) reds[qrow * 8 + w] = sum;
      int colB = (w * 32 + (g << 3)) ^ ((qrow & 7) << 4);
      *(ushort4v*)((char*)lP[pbuf] + qrow * 256 + colB) = pk;
    }
    // rescale output accumulator while lP settles
#pragma unroll
    for (int mf = 0; mf < 4; ++mf) {
      f32x4 rsv = *(const f32x4*)&rs_s[(mf << 4) + (g << 2)];
#pragma unroll
      for (int nf = 0; nf < 4; ++nf)
#pragma unroll
        for (int rr = 0; rr < 4; ++rr) acc_o[mf][nf][rr] *= rsv[rr];
    }
    __syncthreads();  // B3
    if (w == 0) {
      f32x4 a = *(const f32x4*)&reds[lane * 8];
      f32x4 a2 = *(const f32x4*)&reds[lane * 8 + 4];
      float tsum = (a[0] + a[1] + a[2] + a[3]) + (a2[0] + a2[1] + a2[2] + a2[3]);
      l_run = l_run * rs_reg + tsum;
    }

    // ---- Phase C: PV (A = P from lP[pbuf], B = V frags in regs) ----
#pragma unroll
    for (int ks = 0; ks < 4; ++ks) {
#pragma unroll
      for (int mf = 0; mf < 4; ++mf) {
        int qr = (mf << 4) + r16;
        int colB = ((ks << 6) + (g << 4)) ^ ((qr & 7) << 4);
        bf16x8 ap = *(const bf16x8*)((char*)lP[pbuf] + qr * 256 + colB);
#pragma unroll
        for (int nf = 0; nf < 4; ++nf)
          acc_o[mf][nf] = __builtin_amdgcn_mfma_f32_16x16x32_bf16(ap, vf[nf][ks], acc_o[mf][nf], 0, 0, 0);
      }
    }
    // next tile's Phase B writes lP[pbuf^1] and redm (after B1/B2): no race with
    // this tile's lP[pbuf] reads / reds read (all separated by >=1 barrier).
  }

  // ---- epilogue: divide by row-sum, store fp32 ----
  if (w == 0) rs_s[lane] = 1.f / l_run;
  __syncthreads();
#pragma unroll
  for (int mf = 0; mf < 4; ++mf) {
    f32x4 il = *(const f32x4*)&rs_s[(mf << 4) + (g << 2)];
#pragma unroll
    for (int nf = 0; nf < 4; ++nf) {
      int d = (w << 6) + (nf << 4) + r16;
#pragma unroll
      for (int rr = 0; rr < 4; ++rr) {
        int qr = (mf << 4) + (g << 2) + rr;
        out[((size_t)b * 1024 + qt * 64 + qr) * 512 + d] = acc_o[mf][nf][rr] * il[rr];
      }
    }
  }
}

// ---------------------------------------------------------------------------
extern "C" void kernel_launch(void* const* d_in, const int* in_sizes, int n_in,
                              void* d_out, int out_size, void* d_ws, size_t ws_size,
                              hipStream_t stream) {
  const float* query = (const float*)d_in[0];  // [16,1024,512]
  const float* keys  = (const float*)d_in[1];  // [16,4096,512]
  const float* Wq = (const float*)d_in[2];
  const float* bq = (const float*)d_in[3];
  const float* Wk = (const float*)d_in[4];
  const float* bk = (const float*)d_in[5];
  const float* Wv = (const float*)d_in[6];
  const float* bv = (const float*)d_in[7];
  float* out = (float*)d_out;

  char* w = (char*)d_ws;
  unsigned short* query_bf = (unsigned short*)w;                      // 16 MB
  unsigned short* keys_bf  = (unsigned short*)(w + 16777216);         // 64 MB
  unsigned short* q_bf = (unsigned short*)(w + 83886080);             // 16 MB
  unsigned short* k_bf = (unsigned short*)(w + 100663296);            // 64 MB
  unsigned short* vT   = (unsigned short*)(w + 167772160);            // 64 MB
  unsigned short* WqT  = (unsigned short*)(w + 234881024);
  unsigned short* WkT  = WqT + 262144;
  unsigned short* WvT  = WkT + 262144;

  const float scale = 0.04419417382415922f;  // 1/sqrt(512)

  cast_bf16_kernel<<<1024, 256, 0, stream>>>(query, query_bf, 8388608L);
  cast_bf16_kernel<<<2048, 256, 0, stream>>>(keys, keys_bf, 33554432L);
  transpose_w_kernel<<<dim3(16, 16, 3), 256, 0, stream>>>(Wq, Wk, Wv, WqT, WkT, WvT);

  // q = (query@Wq + bq) * scale   [16384 x 512]  (attention scale folded in)
  gemm_nt<0><<<dim3(4, 128), 256, 0, stream>>>(query_bf, WqT, bq, q_bf,
                                               16384, 512, 512, scale);
  // k = keys@Wk + bk    [65536 x 512]
  gemm_nt<0><<<dim3(4, 512), 256, 0, stream>>>(keys_bf, WkT, bk, k_bf,
                                               65536, 512, 512, 1.f);
  // v = k@Wv + bv, stored transposed per batch: vT[b][dim][kvpos]
  gemm_nt<1><<<dim3(4, 512), 256, 0, stream>>>(k_bf, WvT, bv, vT,
                                               65536, 512, 512, 1.f);
  // fused attention
  flash_attn<<<256, 512, 0, stream>>>(q_bf, k_bf, vT, out);

  (void)in_sizes; (void)n_in; (void)out_size; (void)ws_size;
}